// Round 15
// baseline (359.029 us; speedup 1.0000x reference)
//
#include <hip/hip_runtime.h>

#define B_   32
#define HW_  196
#define C_   512
#define M_   (B_*HW_)    // 6272
#define HID_ 128
#define NBLK 18

typedef _Float16 f16;
typedef _Float16 f16x2 __attribute__((ext_vector_type(2)));
typedef _Float16 f16x4 __attribute__((ext_vector_type(4)));
typedef _Float16 f16x8 __attribute__((ext_vector_type(8)));
typedef float    f32x4 __attribute__((ext_vector_type(4)));

__device__ __forceinline__ float gelu_f(float x) {
    float t = tanhf(0.7978845608028654f * (x + 0.044715f * x * x * x));
    return 0.5f * x * (1.0f + t);
}

// async global->LDS, 16B per lane; LDS dest = wave-uniform base + lane*16
__device__ __forceinline__ void gl16(const void* g, void* l) {
    __builtin_amdgcn_global_load_lds((const __attribute__((address_space(1))) unsigned*)g,
                                     (__attribute__((address_space(3))) unsigned*)l, 16, 0, 0);
}

// ---------- merged prologue: x fp32->fp16 (+ zero 3 pooled bufs) AND W transpose ----------
__global__ __launch_bounds__(256) void conv_xw(const float* __restrict__ in,
                                               f16* __restrict__ xout,
                                               float* __restrict__ pooled3,
                                               const float* __restrict__ W,
                                               f16* __restrict__ Wt) {
    __shared__ f16 sh[64][72];
    const int bid = blockIdx.x, tid = threadIdx.x;
    if (bid < 3136) {
        int i = bid * 256 + tid;
        if (bid < 192) pooled3[i] = 0.f;        // 192*256 = 3*32*512
        float4 a = ((const float4*)in)[i];
        f16x4 o; o[0] = (f16)a.x; o[1] = (f16)a.y; o[2] = (f16)a.z; o[3] = (f16)a.w;
        ((f16x4*)xout)[i] = o;
        return;
    }
    const int wjob = bid - 3136;
    const int blk = wjob >> 6, rem = wjob & 63;
    const int k0 = (rem >> 3) << 6, n0 = (rem & 7) << 6;
    const float* Wb = W + (size_t)blk * C_ * C_;
    #pragma unroll
    for (int i = 0; i < 4; ++i) {
        int s = tid + i * 256, r = s >> 4, c4 = (s & 15) << 2;
        float4 v = *(const float4*)&Wb[(size_t)(k0 + r) * C_ + n0 + c4];
        sh[r][c4 + 0] = (f16)v.x; sh[r][c4 + 1] = (f16)v.y;
        sh[r][c4 + 2] = (f16)v.z; sh[r][c4 + 3] = (f16)v.w;
    }
    __syncthreads();
    #pragma unroll
    for (int i = 0; i < 2; ++i) {
        int s = tid + i * 256, r = s >> 3, c8 = (s & 7) << 3;
        f16x8 o;
        #pragma unroll
        for (int j = 0; j < 8; ++j) o[j] = sh[c8 + j][r];
        *(f16x8*)&Wt[(size_t)blk * C_ * C_ + (size_t)(n0 + r) * C_ + k0 + c8] = o;
    }
}

// ---------- MFMA GEMM: out = gelu(A[M,K]@W_blk[K,N] + b) [+ column-sum pooling] ----------
// 64x64x64 tile, 4 waves. Proven best (r6=385, r12=392, r13=353 with aux fixes):
// 2-buffer 32KB drain loop, 784 blocks (3.06/CU, near-uniform), chunked-XCD swizzle.
// GEMM is staged-bytes/~6.4TB/s bound (model fits r6/r8/r9/r10); tile shapes that
// reduce bytes break grid uniformity at M=6272,N=512 — measured dead end.
#define BM 64
#define BN 64
#define BK 64
#define NKT (C_ / BK)   // 8
// LDS layout (halfs): tile[r][c-block] at r*64 + ((c ^ (r&7))<<3), r<64, c<8
__global__ __launch_bounds__(256, 4) void gemm_f16(
    const f16* __restrict__ A, const f16* __restrict__ Wt,
    const float* __restrict__ ball, int blk, f16* __restrict__ out,
    float* __restrict__ pooled)
{
    __shared__ f16 As[2][BM * BK];   // 2 x 8 KB
    __shared__ f16 Ws[2][BN * BK];   // 2 x 8 KB  -> 32 KB total, 4 blocks/CU
    __shared__ float spool[2][BN];   // per-batch-slot column sums (512 B)
    const int tid = threadIdx.x;
    const int wave = tid >> 6, lane = tid & 63;
    const int m15 = lane & 15, q = lane >> 4;
    const int wr = wave >> 1, wc = wave & 1;           // 2x2 wave grid, 32x32 tiles

    // chunked-XCD swizzle (bijective, 784 = 8*98)
    const int lin  = blockIdx.x + 98 * blockIdx.y;     // hw dispatch order
    const int tile = (lin & 7) * 98 + (lin >> 3);      // contiguous chunk per XCD
    const int rb   = tile >> 3, cb = tile & 7;
    const int row0 = rb * BM, col0 = cb * BN;

    const f16* Wb = Wt + (size_t)blk * C_ * C_;
    const float* bias = ball + (size_t)blk * C_;

    // staging: chunk ch = 8 rows x 64k (1KB). lane l loads row ch*8+(l>>3),
    // col-block (l&7)^(srow&7), landing at LDS base+l*16 = swizzled layout.
    const int srow = lane >> 3;
    const int scol = ((lane & 7) ^ (srow & 7)) << 3;   // halfs
    const f16* aSrc[2]; const f16* wSrc[2];
    f16* aDst[2][2]; f16* wDst[2][2];
    #pragma unroll
    for (int i = 0; i < 2; ++i) {
        int ch = wave * 2 + i;                          // 8 chunks cover 64 rows
        aSrc[i] = A  + (size_t)(row0 + ch * 8 + srow) * C_ + scol;
        wSrc[i] = Wb + (size_t)(col0 + ch * 8 + srow) * C_ + scol;
        aDst[0][i] = &As[0][ch * 512]; aDst[1][i] = &As[1][ch * 512];
        wDst[0][i] = &Ws[0][ch * 512]; wDst[1][i] = &Ws[1][ch * 512];
    }

    f32x4 acc[2][2];
    #pragma unroll
    for (int i = 0; i < 2; ++i)
        #pragma unroll
        for (int j = 0; j < 2; ++j) acc[i][j] = (f32x4)0.f;

    // prefetch tile 0 -> buf 0
    #pragma unroll
    for (int i = 0; i < 2; ++i) { gl16(aSrc[i], aDst[0][i]); gl16(wSrc[i], wDst[0][i]); }

    #pragma unroll
    for (int kt = 0; kt < NKT; ++kt) {
        __syncthreads();   // drains this tile's loads + syncs buffer reuse
        int cur = kt & 1;
        if (kt + 1 < NKT) {
            int nxt = cur ^ 1, koff = (kt + 1) * BK;
            #pragma unroll
            for (int i = 0; i < 2; ++i) {
                gl16(aSrc[i] + koff, aDst[nxt][i]);
                gl16(wSrc[i] + koff, wDst[nxt][i]);
            }
        }
        const f16* Ab = &As[cur][0];
        const f16* Bb = &Ws[cur][0];
        #pragma unroll
        for (int kk = 0; kk < BK; kk += 32) {
            f16x8 af[2], bf[2];
            #pragma unroll
            for (int i = 0; i < 2; ++i) {
                int r = wr * 32 + i * 16 + m15;
                int c = (kk >> 3) + q;
                af[i] = *(const f16x8*)&Ab[r * 64 + ((c ^ (r & 7)) << 3)];
            }
            #pragma unroll
            for (int j = 0; j < 2; ++j) {
                int r = wc * 32 + j * 16 + m15;
                int c = (kk >> 3) + q;
                bf[j] = *(const f16x8*)&Bb[r * 64 + ((c ^ (r & 7)) << 3)];
            }
            __builtin_amdgcn_s_setprio(1);
            #pragma unroll
            for (int i = 0; i < 2; ++i)
                #pragma unroll
                for (int j = 0; j < 2; ++j)
                    acc[i][j] = __builtin_amdgcn_mfma_f32_16x16x32_f16(af[i], bf[j], acc[i][j], 0, 0, 0);
            __builtin_amdgcn_s_setprio(0);
        }
    }

    // epilogue: C/D layout col=lane&15, row=quad*4+reg (HW-verified, dtype-indep)
    const bool doPool = (pooled != nullptr);
    if (doPool) {
        if (tid < 2 * BN) ((float*)spool)[tid] = 0.f;
        __syncthreads();
    }
    const int bA = row0 / HW_;                 // first batch this tile touches
    float ps[2][2] = {{0.f, 0.f}, {0.f, 0.f}}; // [batch-slot][j] partial sums
    float bcol[2];
    #pragma unroll
    for (int j = 0; j < 2; ++j) bcol[j] = bias[col0 + wc * 32 + j * 16 + m15];
    #pragma unroll
    for (int i = 0; i < 2; ++i) {
        #pragma unroll
        for (int r = 0; r < 4; ++r) {
            int rloc = wr * 32 + i * 16 + q * 4 + r;
            int row = row0 + rloc;
            int slot = (row / HW_) - bA;       // 0 or 1 (tile spans <= 2 batches)
            #pragma unroll
            for (int j = 0; j < 2; ++j) {
                int col = col0 + wc * 32 + j * 16 + m15;
                float v = gelu_f(acc[i][j][r] + bcol[j]);
                out[(size_t)row * C_ + col] = (f16)v;
                if (doPool) ps[slot & 1][j] += v;
            }
        }
    }
    if (doPool) {
        #pragma unroll
        for (int s = 0; s < 2; ++s)
            #pragma unroll
            for (int j = 0; j < 2; ++j)
                atomicAdd(&spool[s][wc * 32 + j * 16 + m15], ps[s][j]);
        __syncthreads();
        if (tid < 2 * BN) {
            int slot = tid >> 6, colt = tid & 63;
            int b = bA + slot;
            int lastb = (row0 + BM - 1) / HW_;
            if (b <= lastb)                    // slot 1 only if tile spans batches
                atomicAdd(&pooled[(size_t)b * C_ + col0 + colt], spool[slot][colt]);
        }
    }
}

// ---------- fused gating MLP + softmax + routed-add ----------
// grid (B_, 4): block (b, cg) computes gates for its 128 columns IN LDS, then
// applies the routed-add for batch b, cols [128cg,128cg+128), all 196 rows —
// routed element (row,c) needs only gates[b,:,c], which is block-local. Deletes
// the separate routed_add dispatch + boundary; gates never round-trip global.
// Math/order identical to r13's gate_kernel + routed_add_kernel (absmax-identical).
__global__ __launch_bounds__(256) void gate_routed_kernel(const float* __restrict__ pooled,
    const float* __restrict__ fc1w, const float* __restrict__ fc1b,
    const float* __restrict__ fc2w, const float* __restrict__ fc2b,
    const float* __restrict__ gammas, int t,
    f16* __restrict__ nx,
    const f16* __restrict__ a0, const f16* __restrict__ a1, const f16* __restrict__ a2,
    float* __restrict__ outf)
{
    __shared__ float sp[C_];
    __shared__ float sh2[2][HID_];
    __shared__ float sh[HID_];
    __shared__ float sg[3][128];
    const int b = blockIdx.x, cg = blockIdx.y, tid = threadIdx.x;

    float2 pv = *(const float2*)&pooled[b * C_ + 2 * tid];
    sp[2 * tid]     = pv.x * (1.f / 196.f);
    sp[2 * tid + 1] = pv.y * (1.f / 196.f);
    __syncthreads();

    // fc1: 2 threads per output (split C in halves), 256 iters each
    {
        int half = tid >> 7, hh = tid & 127;
        const float* w = fc1w + (size_t)t * C_ * HID_ + hh;
        float s = 0.f;
        int c0 = half * 256;
        for (int c = c0; c < c0 + 256; ++c) s += sp[c] * w[(size_t)c * HID_];
        sh2[half][hh] = s;
    }
    __syncthreads();
    if (tid < HID_) sh[tid] = gelu_f(sh2[0][tid] + sh2[1][tid] + fc1b[t * HID_ + tid]);
    __syncthreads();

    if (tid < 128) {
        int c = cg * 128 + tid;
        const float* w2 = fc2w + (size_t)t * HID_ * (3 * C_) + c;
        float l0 = fc2b[t * 3 * C_ + c];
        float l1 = fc2b[t * 3 * C_ + C_ + c];
        float l2 = fc2b[t * 3 * C_ + 2 * C_ + c];
        for (int j = 0; j < HID_; ++j) {
            float h = sh[j];
            const float* r = w2 + (size_t)j * 3 * C_;
            l0 += h * r[0];
            l1 += h * r[C_];
            l2 += h * r[2 * C_];
        }
        float m  = fmaxf(l0, fmaxf(l1, l2));
        float e0 = expf(l0 - m), e1 = expf(l1 - m), e2 = expf(l2 - m);
        float inv = 1.f / (e0 + e1 + e2);
        sg[0][tid] = e0 * inv;
        sg[1][tid] = e1 * inv;
        sg[2][tid] = e2 * inv;
    }
    __syncthreads();

    // routed-add: batch b, cols [cg*128, cg*128+128), rows 0..195.
    // 196 rows x 16 f16x8-chunks = 3136 vector jobs; consecutive tids cover
    // consecutive 16B chunks within a row (coalesced 256B segments).
    const float gamma = gammas[t];
    for (int j = tid; j < 196 * 16; j += 256) {
        int row = j >> 4, ch = j & 15;
        size_t e = ((size_t)(b * HW_ + row)) * C_ + cg * 128 + ch * 8;
        f16x8 xn = *(const f16x8*)&nx[e];
        f16x8 x0 = *(const f16x8*)&a0[e];
        f16x8 x1 = *(const f16x8*)&a1[e];
        f16x8 x2 = *(const f16x8*)&a2[e];
        int cb8 = ch * 8;
        float r[8];
        #pragma unroll
        for (int el = 0; el < 8; ++el)
            r[el] = (float)xn[el] + gamma * (sg[0][cb8 + el] * (float)x0[el]
                    + sg[1][cb8 + el] * (float)x1[el] + sg[2][cb8 + el] * (float)x2[el]);
        if (t == 2) {
            float4* o = (float4*)&outf[e];
            o[0] = make_float4(r[0], r[1], r[2], r[3]);
            o[1] = make_float4(r[4], r[5], r[6], r[7]);
        } else {
            f16x8 o;
            #pragma unroll
            for (int el = 0; el < 8; ++el) o[el] = (f16)r[el];
            *(f16x8*)&nx[e] = o;
        }
    }
}

extern "C" void kernel_launch(void* const* d_in, const int* in_sizes, int n_in,
                              void* d_out, int out_size, void* d_ws, size_t ws_size,
                              hipStream_t stream)
{
    const float* x      = (const float*)d_in[0];
    const float* blockw = (const float*)d_in[1];
    const float* blockb = (const float*)d_in[2];
    const float* fc1w   = (const float*)d_in[3];
    const float* fc1b   = (const float*)d_in[4];
    const float* fc2w   = (const float*)d_in[5];
    const float* fc2b   = (const float*)d_in[6];
    const float* gammas = (const float*)d_in[7];
    float* out = (float*)d_out;

    const size_t NB = (size_t)M_ * C_;            // 3,211,264 elems/activation
    f16* Wt = (f16*)d_ws;                          // 18*512*512 halfs = 9.44MB
    f16* P0 = Wt + (size_t)NBLK * C_ * C_;
    f16* P1 = P0 + NB;
    f16* A0 = P0 + 2 * NB;
    f16* A1 = P0 + 3 * NB;
    f16* A2 = P0 + 4 * NB;
    float* pooled3 = (float*)(P0 + 5 * NB);        // [3][32][512] per-target column sums

    conv_xw<<<3136 + 64 * NBLK, 256, 0, stream>>>(x, P1, pooled3, blockw, Wt);

    // x(fp16)=P1 feeds block 0; anchors (blocks 1,4,9 outputs) pinned A0/A1/A2
    const f16* ins[NBLK]  = {P1, P0, A0, P0, P1, A1, P0, P1, P0, P1, A2, P0, P1, P0, P1, P0, P1, P0};
    f16*       outs[NBLK] = {P0, A0, P0, P1, A1, P0, P1, P0, P1, A2, P0, P1, P0, P1, P0, P1, P0, P1};

    for (int i = 0; i < NBLK; ++i) {
        int t = (i == 11) ? 0 : (i == 14) ? 1 : (i == 17) ? 2 : -1;
        float* pooledT = (t >= 0) ? pooled3 + (size_t)t * B_ * C_ : (float*)nullptr;
        gemm_f16<<<dim3(M_ / BM, C_ / BN), 256, 0, stream>>>(
            ins[i], Wt, blockb, i, outs[i], pooledT);
        if (t >= 0)
            gate_routed_kernel<<<dim3(B_, 4), 256, 0, stream>>>(
                pooledT, fc1w, fc1b, fc2w, fc2b, gammas, t,
                outs[i], A0, A1, A2, (t == 2) ? out : (float*)nullptr);
    }
}